// Round 1
// baseline (1889.224 us; speedup 1.0000x reference)
//
#include <hip/hip_runtime.h>

#define NN 100000
#define NE 3200000
#define LN_EPS 1e-5f

// ---------------- degree ----------------
__global__ void k_init_deg(float* __restrict__ deg) {
    int i = blockIdx.x * blockDim.x + threadIdx.x;
    if (i < NN) deg[i] = 1.0f;  // self-loop weight
}

__global__ void k_deg_scatter(const int* __restrict__ col, const float* __restrict__ w,
                              float* __restrict__ deg) {
    int e = blockIdx.x * blockDim.x + threadIdx.x;
    if (e < NE) atomicAdd(&deg[col[e]], w[e]);
}

__global__ void k_dinv_agg1init(const float* __restrict__ deg, const float* __restrict__ x,
                                float* __restrict__ dinv, float* __restrict__ agg1) {
    int i = blockIdx.x * blockDim.x + threadIdx.x;
    if (i >= NN) return;
    float d = deg[i];
    dinv[i] = rsqrtf(d);
    float sn = 1.0f / d;          // self-loop norm dinv^2
    agg1[2 * i]     = x[2 * i]     * sn;
    agg1[2 * i + 1] = x[2 * i + 1] * sn;
}

// ---------------- layer 1 scatter (2 features) ----------------
__global__ void k_scatter1(const int* __restrict__ row, const int* __restrict__ col,
                           const float* __restrict__ w, const float* __restrict__ dinv,
                           const float* __restrict__ x, float* __restrict__ agg1) {
    int e = blockIdx.x * blockDim.x + threadIdx.x;
    if (e >= NE) return;
    int r = row[e], c = col[e];
    float nrm = dinv[r] * w[e] * dinv[c];
    float2 xv = *(const float2*)(x + 2 * r);
    atomicAdd(&agg1[2 * c],     nrm * xv.x);
    atomicAdd(&agg1[2 * c + 1], nrm * xv.y);
}

// ---------------- layer 1 node update: x1 = relu(LN(agg1@W1 + b1 + x@rW1 + rb1)) ----------------
__global__ void k_layer1(const float* __restrict__ agg1, const float* __restrict__ x,
                         const float* __restrict__ W1, const float* __restrict__ b1,
                         const float* __restrict__ rW1, const float* __restrict__ rb1,
                         const float* __restrict__ g1, const float* __restrict__ be1,
                         float* __restrict__ x1) {
    int node = (blockIdx.x * blockDim.x + threadIdx.x) >> 6;
    int lane = threadIdx.x & 63;
    if (node >= NN) return;
    float a0 = agg1[2 * node], a1 = agg1[2 * node + 1];
    float xa = x[2 * node],    xb = x[2 * node + 1];
    float v = a0 * W1[lane] + a1 * W1[64 + lane] + b1[lane]
            + xa * rW1[lane] + xb * rW1[64 + lane] + rb1[lane];
    // LayerNorm over 64 lanes
    float s = v;
    #pragma unroll
    for (int m = 32; m >= 1; m >>= 1) s += __shfl_xor(s, m, 64);
    float mean = s * (1.0f / 64.0f);
    float e = v - mean;
    float s2 = e * e;
    #pragma unroll
    for (int m = 32; m >= 1; m >>= 1) s2 += __shfl_xor(s2, m, 64);
    float var = s2 * (1.0f / 64.0f);
    float y = e * rsqrtf(var + LN_EPS) * g1[lane] + be1[lane];
    x1[node * 64 + lane] = fmaxf(y, 0.0f);
}

// ---------------- t2 = x1@W2 ; agg2_init = t2/deg + b2 + x1@rW2 + rb2 ----------------
__global__ void k_t2(const float* __restrict__ x1, const float* __restrict__ deg,
                     const float* __restrict__ W2, const float* __restrict__ b2,
                     const float* __restrict__ rW2, const float* __restrict__ rb2,
                     float* __restrict__ t2, float* __restrict__ agg2) {
    __shared__ float sm[4][64];
    int wid  = threadIdx.x >> 6;
    int lane = threadIdx.x & 63;
    int node = blockIdx.x * 4 + wid;
    float v = 0.0f;
    if (node < NN) v = x1[node * 64 + lane];
    sm[wid][lane] = v;
    __syncthreads();
    int k = lane & 31;
    bool isres = lane >= 32;
    const float* Wm = isres ? rW2 : W2;
    float acc = 0.0f;
    #pragma unroll
    for (int j = 0; j < 64; ++j)
        acc += sm[wid][j] * Wm[j * 32 + k];
    float other = __shfl_xor(acc, 32, 64);  // lane<32 gets the rW2 dot, lane>=32 gets W2 dot
    if (node < NN && !isres) {
        t2[node * 32 + k] = acc;
        float sn = 1.0f / deg[node];
        agg2[node * 32 + k] = acc * sn + b2[k] + other + rb2[k];
    }
}

// ---------------- layer 2 scatter (32 features, 8 threads/edge, float4) ----------------
__global__ void k_scatter2(const int* __restrict__ row, const int* __restrict__ col,
                           const float* __restrict__ w, const float* __restrict__ dinv,
                           const float* __restrict__ t2, float* __restrict__ agg2) {
    int t = blockIdx.x * blockDim.x + threadIdx.x;
    int e = t >> 3;
    int f = (t & 7) * 4;
    if (e >= NE) return;
    int r = row[e], c = col[e];
    float nrm = dinv[r] * w[e] * dinv[c];
    float4 tv = *(const float4*)(t2 + r * 32 + f);
    float* dst = agg2 + c * 32 + f;
    atomicAdd(dst + 0, nrm * tv.x);
    atomicAdd(dst + 1, nrm * tv.y);
    atomicAdd(dst + 2, nrm * tv.z);
    atomicAdd(dst + 3, nrm * tv.w);
}

// ---------------- final: LN+relu, logits, proj, normalize ----------------
__global__ void k_final(const float* __restrict__ agg2,
                        const float* __restrict__ g2, const float* __restrict__ be2,
                        const float* __restrict__ fcW, const float* __restrict__ fcb,
                        const float* __restrict__ pW, const float* __restrict__ pb,
                        float* __restrict__ out) {
    int node = (blockIdx.x * blockDim.x + threadIdx.x) >> 5;
    int k = threadIdx.x & 31;
    if (node >= NN) return;
    float v = agg2[node * 32 + k];
    float s = v;
    #pragma unroll
    for (int m = 16; m >= 1; m >>= 1) s += __shfl_xor(s, m, 32);
    float mean = s * (1.0f / 32.0f);
    float e = v - mean;
    float s2 = e * e;
    #pragma unroll
    for (int m = 16; m >= 1; m >>= 1) s2 += __shfl_xor(s2, m, 32);
    float var = s2 * (1.0f / 32.0f);
    float x2 = fmaxf(e * rsqrtf(var + LN_EPS) * g2[k] + be2[k], 0.0f);
    // logits = x2 . fcW + fcb
    float lg = x2 * fcW[k];
    #pragma unroll
    for (int m = 16; m >= 1; m >>= 1) lg += __shfl_xor(lg, m, 32);
    if (k == 0) out[node] = lg + fcb[0];
    // proj[k] = sum_j x2[j] * pW[j*32+k] + pb[k]
    float acc = pb[k];
    #pragma unroll
    for (int j = 0; j < 32; ++j) {
        float xj = __shfl(x2, j, 32);
        acc += xj * pW[j * 32 + k];
    }
    float n2 = acc * acc;
    #pragma unroll
    for (int m = 16; m >= 1; m >>= 1) n2 += __shfl_xor(n2, m, 32);
    float nrm = sqrtf(n2);
    out[NN + node * 32 + k] = acc / fmaxf(nrm, 1e-12f);
}

extern "C" void kernel_launch(void* const* d_in, const int* in_sizes, int n_in,
                              void* d_out, int out_size, void* d_ws, size_t ws_size,
                              hipStream_t stream) {
    const float* x   = (const float*)d_in[0];
    const float* ew  = (const float*)d_in[1];
    const float* W1  = (const float*)d_in[2];
    const float* b1  = (const float*)d_in[3];
    const float* rW1 = (const float*)d_in[4];
    const float* rb1 = (const float*)d_in[5];
    const float* g1  = (const float*)d_in[6];
    const float* be1 = (const float*)d_in[7];
    const float* W2  = (const float*)d_in[8];
    const float* b2  = (const float*)d_in[9];
    const float* rW2 = (const float*)d_in[10];
    const float* rb2 = (const float*)d_in[11];
    const float* g2  = (const float*)d_in[12];
    const float* be2 = (const float*)d_in[13];
    const float* fcW = (const float*)d_in[14];
    const float* fcb = (const float*)d_in[15];
    const float* pW  = (const float*)d_in[16];
    const float* pb  = (const float*)d_in[17];
    const int*   ei  = (const int*)d_in[18];
    const int* row = ei;
    const int* col = ei + NE;

    float* ws   = (float*)d_ws;
    float* deg  = ws;  ws += NN;
    float* dinv = ws;  ws += NN;
    float* agg1 = ws;  ws += 2 * NN;
    float* x1   = ws;  ws += 64 * NN;
    float* t2   = ws;  ws += 32 * NN;
    float* agg2 = ws;  ws += 32 * NN;

    float* out = (float*)d_out;
    const int TB = 256;

    k_init_deg<<<(NN + TB - 1) / TB, TB, 0, stream>>>(deg);
    k_deg_scatter<<<(NE + TB - 1) / TB, TB, 0, stream>>>(col, ew, deg);
    k_dinv_agg1init<<<(NN + TB - 1) / TB, TB, 0, stream>>>(deg, x, dinv, agg1);
    k_scatter1<<<(NE + TB - 1) / TB, TB, 0, stream>>>(row, col, ew, dinv, x, agg1);
    k_layer1<<<(NN * 64 + TB - 1) / TB, TB, 0, stream>>>(agg1, x, W1, b1, rW1, rb1, g1, be1, x1);
    k_t2<<<(NN + 3) / 4, TB, 0, stream>>>(x1, deg, W2, b2, rW2, rb2, t2, agg2);
    k_scatter2<<<(int)(((long)NE * 8 + TB - 1) / TB), TB, 0, stream>>>(row, col, ew, dinv, t2, agg2);
    k_final<<<(NN * 32 + TB - 1) / TB, TB, 0, stream>>>(agg2, g2, be2, fcW, fcb, pW, pb, out);
}

// Round 2
// 595.098 us; speedup vs baseline: 3.1746x; 3.1746x over previous
//
#include <hip/hip_runtime.h>

#define NN 100000
#define NE 3200000
#define LN_EPS 1e-5f
#define NBLK 391   // ceil(NN/256)

// ---------------- CSR build: histogram ----------------
__global__ void k_hist(const int* __restrict__ col, int* __restrict__ cnt) {
    int e = blockIdx.x * blockDim.x + threadIdx.x;
    if (e < NE) atomicAdd(&cnt[col[e]], 1);
}

// ---------------- scan step 1: per-block sums ----------------
__global__ void k_scan1(const int* __restrict__ cnt, int* __restrict__ bsum) {
    int i = blockIdx.x * 256 + threadIdx.x;
    int v = (i < NN) ? cnt[i] : 0;
    #pragma unroll
    for (int m = 32; m >= 1; m >>= 1) v += __shfl_xor(v, m, 64);
    __shared__ int sm[4];
    if ((threadIdx.x & 63) == 0) sm[threadIdx.x >> 6] = v;
    __syncthreads();
    if (threadIdx.x == 0) bsum[blockIdx.x] = sm[0] + sm[1] + sm[2] + sm[3];
}

// ---------------- scan step 2: exclusive scan of block sums (single block) ----------------
__global__ void k_scan2(int* __restrict__ bsum) {
    __shared__ int sm[512];
    int t = threadIdx.x;
    int v = (t < NBLK) ? bsum[t] : 0;
    sm[t] = v;
    __syncthreads();
    for (int off = 1; off < 512; off <<= 1) {
        int u = (t >= off) ? sm[t - off] : 0;
        __syncthreads();
        sm[t] += u;
        __syncthreads();
    }
    if (t < NBLK) bsum[t] = sm[t] - v;  // exclusive
}

// ---------------- scan step 3: per-element exclusive positions ----------------
__global__ void k_scan3(const int* __restrict__ cnt, const int* __restrict__ bsum,
                        int* __restrict__ ptr, int* __restrict__ ptrw) {
    int i = blockIdx.x * 256 + threadIdx.x;
    int lane = threadIdx.x & 63;
    int v = (i < NN) ? cnt[i] : 0;
    int inc = v;
    #pragma unroll
    for (int off = 1; off < 64; off <<= 1) {
        int u = __shfl_up(inc, off, 64);
        if (lane >= off) inc += u;
    }
    __shared__ int wsum[4];
    if (lane == 63) wsum[threadIdx.x >> 6] = inc;
    __syncthreads();
    int w = threadIdx.x >> 6;
    int woff = 0;
    for (int j = 0; j < 4; ++j) if (j < w) woff += wsum[j];
    int ex = bsum[blockIdx.x] + woff + inc - v;
    if (i < NN) { ptr[i] = ex; ptrw[i] = ex; }
}

// ---------------- CSR build: scatter edges (packed {row, w}) ----------------
__global__ void k_build_csr(const int* __restrict__ row, const int* __restrict__ col,
                            const float* __restrict__ w, int* __restrict__ ptrw,
                            int2* __restrict__ csr) {
    int e = blockIdx.x * blockDim.x + threadIdx.x;
    if (e >= NE) return;
    int c = col[e];
    int pos = atomicAdd(&ptrw[c], 1);
    csr[pos] = make_int2(row[e], __float_as_int(w[e]));
}

// ---------------- deg/dinv from CSR (no atomics) ----------------
__global__ void k_deg(const int* __restrict__ ptr, const int* __restrict__ cnt,
                      const int2* __restrict__ csr, float* __restrict__ dinv) {
    int t = blockIdx.x * blockDim.x + threadIdx.x;
    int node = t >> 5, lane = t & 31;
    if (node >= NN) return;
    int start = ptr[node], n = cnt[node];
    float s = 0.0f;
    for (int j = lane; j < n; j += 32) s += __int_as_float(csr[start + j].y);
    #pragma unroll
    for (int m = 16; m >= 1; m >>= 1) s += __shfl_xor(s, m, 32);
    if (lane == 0) dinv[node] = rsqrtf(s + 1.0f);  // +1 self-loop
}

// ---------------- layer 1 aggregation: gather (2 features) ----------------
__global__ void k_agg1(const int* __restrict__ ptr, const int* __restrict__ cnt,
                       const int2* __restrict__ csr, const float* __restrict__ dinv,
                       const float* __restrict__ x, float* __restrict__ agg1) {
    int t = blockIdx.x * blockDim.x + threadIdx.x;
    int node = t >> 5, lane = t & 31;
    if (node >= NN) return;
    int start = ptr[node], n = cnt[node];
    float a0 = 0.0f, a1 = 0.0f;
    for (int j = lane; j < n; j += 32) {
        int2 e = csr[start + j];
        int r = e.x;
        float cf = __int_as_float(e.y) * dinv[r];
        float2 xv = *(const float2*)(x + 2 * r);
        a0 += cf * xv.x;
        a1 += cf * xv.y;
    }
    #pragma unroll
    for (int m = 16; m >= 1; m >>= 1) {
        a0 += __shfl_xor(a0, m, 32);
        a1 += __shfl_xor(a1, m, 32);
    }
    if (lane == 0) {
        float di = dinv[node];
        float2 xs = *(const float2*)(x + 2 * node);
        agg1[2 * node]     = di * a0 + di * di * xs.x;
        agg1[2 * node + 1] = di * a1 + di * di * xs.y;
    }
}

// ---------------- fused layer1 (LN+relu) + t2 = x1@W2 + agg2 init ----------------
__global__ void k_l1t2(const float* __restrict__ agg1, const float* __restrict__ x,
                       const float* __restrict__ dinv,
                       const float* __restrict__ W1, const float* __restrict__ b1,
                       const float* __restrict__ rW1, const float* __restrict__ rb1,
                       const float* __restrict__ g1, const float* __restrict__ be1,
                       const float* __restrict__ W2, const float* __restrict__ b2,
                       const float* __restrict__ rW2, const float* __restrict__ rb2,
                       float* __restrict__ t2, float* __restrict__ agg2) {
    __shared__ float sm[4][64];
    int wid = threadIdx.x >> 6, lane = threadIdx.x & 63;
    int node = blockIdx.x * 4 + wid;
    int nd = node < NN ? node : NN - 1;
    float a0 = agg1[2 * nd], a1 = agg1[2 * nd + 1];
    float xa = x[2 * nd], xb = x[2 * nd + 1];
    float v = a0 * W1[lane] + a1 * W1[64 + lane] + b1[lane]
            + xa * rW1[lane] + xb * rW1[64 + lane] + rb1[lane];
    float s = v;
    #pragma unroll
    for (int m = 32; m >= 1; m >>= 1) s += __shfl_xor(s, m, 64);
    float mean = s * (1.0f / 64.0f);
    float e = v - mean;
    float s2 = e * e;
    #pragma unroll
    for (int m = 32; m >= 1; m >>= 1) s2 += __shfl_xor(s2, m, 64);
    float var = s2 * (1.0f / 64.0f);
    float x1v = fmaxf(e * rsqrtf(var + LN_EPS) * g1[lane] + be1[lane], 0.0f);
    sm[wid][lane] = x1v;
    __syncthreads();
    int k = lane & 31;
    bool isres = lane >= 32;
    const float* Wm = isres ? rW2 : W2;
    float acc = 0.0f;
    #pragma unroll
    for (int j = 0; j < 64; ++j) acc += sm[wid][j] * Wm[j * 32 + k];
    float other = __shfl_xor(acc, 32, 64);
    if (node < NN && !isres) {
        t2[node * 32 + k] = acc;
        float di = dinv[node];
        agg2[node * 32 + k] = acc * di * di + b2[k] + other + rb2[k];
    }
}

// ---------------- layer 2 aggregation: gather (32 features, coalesced) ----------------
__global__ void k_agg2(const int* __restrict__ ptr, const int* __restrict__ cnt,
                       const int2* __restrict__ csr, const float* __restrict__ dinv,
                       const float* __restrict__ t2, float* __restrict__ agg2) {
    int t = blockIdx.x * blockDim.x + threadIdx.x;
    int node = t >> 5, k = t & 31;
    if (node >= NN) return;
    int start = ptr[node], n = cnt[node];
    float acc = 0.0f;
    #pragma unroll 4
    for (int j = 0; j < n; ++j) {
        int2 e = csr[start + j];             // lane-uniform broadcast
        int r = e.x;
        float cf = __int_as_float(e.y) * dinv[r];
        acc += cf * t2[r * 32 + k];          // 32-lane coalesced 128B
    }
    float di = dinv[node];
    agg2[node * 32 + k] += di * acc;
}

// ---------------- final: LN+relu, logits, proj, normalize ----------------
__global__ void k_final(const float* __restrict__ agg2,
                        const float* __restrict__ g2, const float* __restrict__ be2,
                        const float* __restrict__ fcW, const float* __restrict__ fcb,
                        const float* __restrict__ pW, const float* __restrict__ pb,
                        float* __restrict__ out) {
    int node = (blockIdx.x * blockDim.x + threadIdx.x) >> 5;
    int k = threadIdx.x & 31;
    if (node >= NN) return;
    float v = agg2[node * 32 + k];
    float s = v;
    #pragma unroll
    for (int m = 16; m >= 1; m >>= 1) s += __shfl_xor(s, m, 32);
    float mean = s * (1.0f / 32.0f);
    float e = v - mean;
    float s2 = e * e;
    #pragma unroll
    for (int m = 16; m >= 1; m >>= 1) s2 += __shfl_xor(s2, m, 32);
    float var = s2 * (1.0f / 32.0f);
    float x2 = fmaxf(e * rsqrtf(var + LN_EPS) * g2[k] + be2[k], 0.0f);
    float lg = x2 * fcW[k];
    #pragma unroll
    for (int m = 16; m >= 1; m >>= 1) lg += __shfl_xor(lg, m, 32);
    if (k == 0) out[node] = lg + fcb[0];
    float acc = pb[k];
    #pragma unroll
    for (int j = 0; j < 32; ++j) {
        float xj = __shfl(x2, j, 32);
        acc += xj * pW[j * 32 + k];
    }
    float n2 = acc * acc;
    #pragma unroll
    for (int m = 16; m >= 1; m >>= 1) n2 += __shfl_xor(n2, m, 32);
    float nrm = sqrtf(n2);
    out[NN + node * 32 + k] = acc / fmaxf(nrm, 1e-12f);
}

extern "C" void kernel_launch(void* const* d_in, const int* in_sizes, int n_in,
                              void* d_out, int out_size, void* d_ws, size_t ws_size,
                              hipStream_t stream) {
    const float* x   = (const float*)d_in[0];
    const float* ew  = (const float*)d_in[1];
    const float* W1  = (const float*)d_in[2];
    const float* b1  = (const float*)d_in[3];
    const float* rW1 = (const float*)d_in[4];
    const float* rb1 = (const float*)d_in[5];
    const float* g1  = (const float*)d_in[6];
    const float* be1 = (const float*)d_in[7];
    const float* W2  = (const float*)d_in[8];
    const float* b2  = (const float*)d_in[9];
    const float* rW2 = (const float*)d_in[10];
    const float* rb2 = (const float*)d_in[11];
    const float* g2  = (const float*)d_in[12];
    const float* be2 = (const float*)d_in[13];
    const float* fcW = (const float*)d_in[14];
    const float* fcb = (const float*)d_in[15];
    const float* pW  = (const float*)d_in[16];
    const float* pb  = (const float*)d_in[17];
    const int*   ei  = (const int*)d_in[18];
    const int* row = ei;
    const int* col = ei + NE;

    // workspace layout (csr first for 8B alignment)
    char* p = (char*)d_ws;
    int2*  csr  = (int2*)p;            p += (size_t)NE * 8;
    float* dinv = (float*)p;           p += (size_t)NN * 4;
    float* agg1 = (float*)p;           p += (size_t)2 * NN * 4;
    float* t2   = (float*)p;           p += (size_t)32 * NN * 4;
    float* agg2 = (float*)p;           p += (size_t)32 * NN * 4;
    int*   cnt  = (int*)p;             p += (size_t)NN * 4;
    int*   ptr  = (int*)p;             p += (size_t)NN * 4;
    int*   ptrw = (int*)p;             p += (size_t)NN * 4;
    int*   bsum = (int*)p;             p += 512 * 4;

    float* out = (float*)d_out;
    const int TB = 256;
    const int EB = (NE + TB - 1) / TB;
    const int NODE32 = (NN * 32 + TB - 1) / TB;

    hipMemsetAsync(cnt, 0, (size_t)NN * 4, stream);
    k_hist<<<EB, TB, 0, stream>>>(col, cnt);
    k_scan1<<<NBLK, 256, 0, stream>>>(cnt, bsum);
    k_scan2<<<1, 512, 0, stream>>>(bsum);
    k_scan3<<<NBLK, 256, 0, stream>>>(cnt, bsum, ptr, ptrw);
    k_build_csr<<<EB, TB, 0, stream>>>(row, col, ew, ptrw, csr);
    k_deg<<<NODE32, TB, 0, stream>>>(ptr, cnt, csr, dinv);
    k_agg1<<<NODE32, TB, 0, stream>>>(ptr, cnt, csr, dinv, x, agg1);
    k_l1t2<<<(NN + 3) / 4, TB, 0, stream>>>(agg1, x, dinv, W1, b1, rW1, rb1, g1, be1,
                                            W2, b2, rW2, rb2, t2, agg2);
    k_agg2<<<NODE32, TB, 0, stream>>>(ptr, cnt, csr, dinv, t2, agg2);
    k_final<<<NODE32, TB, 0, stream>>>(agg2, g2, be2, fcW, fcb, pW, pb, out);
}

// Round 3
// 416.825 us; speedup vs baseline: 4.5324x; 1.4277x over previous
//
#include <hip/hip_runtime.h>

#define NN 100000
#define NE 3200000
#define LN_EPS 1e-5f
#define NBLK 391        // ceil(NN/256)
#define NBUCK 196       // ceil(NN/512), bucket = col >> 9
#define TILE 4096       // edges per partition block
#define NTILE 782       // ceil(NE/TILE)

// ---------------- CSR build: per-node histogram ----------------
__global__ void k_hist(const int* __restrict__ col, int* __restrict__ cnt) {
    int e = blockIdx.x * blockDim.x + threadIdx.x;
    if (e < NE) atomicAdd(&cnt[col[e]], 1);
}

// ---------------- scan step 1: per-block sums ----------------
__global__ void k_scan1(const int* __restrict__ cnt, int* __restrict__ bsum) {
    int i = blockIdx.x * 256 + threadIdx.x;
    int v = (i < NN) ? cnt[i] : 0;
    #pragma unroll
    for (int m = 32; m >= 1; m >>= 1) v += __shfl_xor(v, m, 64);
    __shared__ int sm[4];
    if ((threadIdx.x & 63) == 0) sm[threadIdx.x >> 6] = v;
    __syncthreads();
    if (threadIdx.x == 0) bsum[blockIdx.x] = sm[0] + sm[1] + sm[2] + sm[3];
}

// ---------------- scan step 2: exclusive scan of block sums ----------------
__global__ void k_scan2(int* __restrict__ bsum) {
    __shared__ int sm[512];
    int t = threadIdx.x;
    int v = (t < NBLK) ? bsum[t] : 0;
    sm[t] = v;
    __syncthreads();
    for (int off = 1; off < 512; off <<= 1) {
        int u = (t >= off) ? sm[t - off] : 0;
        __syncthreads();
        sm[t] += u;
        __syncthreads();
    }
    if (t < NBLK) bsum[t] = sm[t] - v;  // exclusive
}

// ---------------- scan step 3: per-node exclusive positions ----------------
__global__ void k_scan3(const int* __restrict__ cnt, const int* __restrict__ bsum,
                        int* __restrict__ ptr) {
    int i = blockIdx.x * 256 + threadIdx.x;
    int lane = threadIdx.x & 63;
    int v = (i < NN) ? cnt[i] : 0;
    int inc = v;
    #pragma unroll
    for (int off = 1; off < 64; off <<= 1) {
        int u = __shfl_up(inc, off, 64);
        if (lane >= off) inc += u;
    }
    __shared__ int wsum[4];
    if (lane == 63) wsum[threadIdx.x >> 6] = inc;
    __syncthreads();
    int w = threadIdx.x >> 6;
    int woff = 0;
    for (int j = 0; j < 4; ++j) if (j < w) woff += wsum[j];
    int ex = bsum[blockIdx.x] + woff + inc - v;
    if (i < NN) ptr[i] = ex;
}

// ---------------- init bucket cursors from ptr ----------------
__global__ void k_gcur(const int* __restrict__ ptr, int* __restrict__ gcur) {
    int b = blockIdx.x * blockDim.x + threadIdx.x;
    if (b < NBUCK) gcur[b] = ptr[b * 512];
}

// ---------------- partition pass A: bucket-sort tiles, near-coalesced flush ----------------
__global__ __launch_bounds__(256) void k_partA(
        const int* __restrict__ row, const int* __restrict__ col,
        const float* __restrict__ w, int* __restrict__ gcur,
        int2* __restrict__ tmp) {
    __shared__ int2 sbuf[TILE];     // 32 KB
    __shared__ int  gpos[TILE];     // 16 KB
    __shared__ int  lhist[NBUCK];
    __shared__ int  lofs[NBUCK];
    __shared__ int  lbase[NBUCK];
    __shared__ int  wsum[4];
    int t = threadIdx.x;
    long base_e = (long)blockIdx.x * TILE;
    int nt = NE - base_e < TILE ? (int)(NE - base_e) : TILE;

    for (int b = t; b < NBUCK; b += 256) lhist[b] = 0;
    __syncthreads();

    int er[16]; int ec[16]; float ewv[16];
    #pragma unroll
    for (int i = 0; i < 16; ++i) {
        int j = t + i * 256;
        if (j < nt) {
            int e = (int)base_e + j;
            er[i] = row[e]; ec[i] = col[e]; ewv[i] = w[e];
            atomicAdd(&lhist[ec[i] >> 9], 1);
        } else { er[i] = -1; ec[i] = 0; ewv[i] = 0.0f; }
    }
    __syncthreads();

    // block-exclusive-scan of lhist (padded to 256) + reserve global runs
    {
        int v = (t < NBUCK) ? lhist[t] : 0;
        int lane = t & 63;
        int inc = v;
        #pragma unroll
        for (int off = 1; off < 64; off <<= 1) {
            int u = __shfl_up(inc, off, 64);
            if (lane >= off) inc += u;
        }
        if (lane == 63) wsum[t >> 6] = inc;
        __syncthreads();
        int wv = t >> 6;
        int woff = 0;
        for (int j = 0; j < 4; ++j) if (j < wv) woff += wsum[j];
        if (t < NBUCK) {
            lofs[t] = woff + inc - v;
            lbase[t] = atomicAdd(&gcur[t], v);
        }
    }
    __syncthreads();
    for (int b = t; b < NBUCK; b += 256) lhist[b] = 0;   // reuse as rank counters
    __syncthreads();

    #pragma unroll
    for (int i = 0; i < 16; ++i) {
        if (er[i] >= 0) {
            int b = ec[i] >> 9;
            int r = atomicAdd(&lhist[b], 1);
            int slot = lofs[b] + r;
            sbuf[slot] = make_int2(er[i] | ((ec[i] & 511) << 17), __float_as_int(ewv[i]));
            gpos[slot] = lbase[b] + r;
        }
    }
    __syncthreads();

    #pragma unroll
    for (int i = 0; i < 16; ++i) {
        int j = t + i * 256;
        if (j < nt) tmp[gpos[j]] = sbuf[j];
    }
}

// ---------------- partition pass B: in-bucket scatter to exact per-node slots ----------------
__global__ __launch_bounds__(512) void k_partB(
        const int* __restrict__ ptr, const int2* __restrict__ tmp,
        int2* __restrict__ csr) {
    __shared__ int cur[512];
    int b = blockIdx.x;
    int t = threadIdx.x;
    int node0 = b * 512;
    int gn = node0 + t;
    cur[t] = (gn < NN) ? ptr[gn] : 0;
    int start = ptr[node0];
    int end = (b < NBUCK - 1) ? ptr[node0 + 512] : NE;
    __syncthreads();
    for (int j = start + t; j < end; j += 512) {
        int2 rec = tmp[j];
        int cl = ((unsigned)rec.x) >> 17;
        int r = rec.x & 0x1FFFF;
        int pos = atomicAdd(&cur[cl], 1);
        csr[pos] = make_int2(r, rec.y);
    }
}

// ---------------- deg/dinv from CSR ----------------
__global__ void k_deg(const int* __restrict__ ptr, const int* __restrict__ cnt,
                      const int2* __restrict__ csr, float* __restrict__ dinv) {
    int t = blockIdx.x * blockDim.x + threadIdx.x;
    int node = t >> 5, lane = t & 31;
    if (node >= NN) return;
    int start = ptr[node], n = cnt[node];
    float s = 0.0f;
    for (int j = lane; j < n; j += 32) s += __int_as_float(csr[start + j].y);
    #pragma unroll
    for (int m = 16; m >= 1; m >>= 1) s += __shfl_xor(s, m, 32);
    if (lane == 0) dinv[node] = rsqrtf(s + 1.0f);  // +1 self-loop
}

// ---------------- layer 1 aggregation: gather (2 features) ----------------
__global__ void k_agg1(const int* __restrict__ ptr, const int* __restrict__ cnt,
                       const int2* __restrict__ csr, const float* __restrict__ dinv,
                       const float* __restrict__ x, float* __restrict__ agg1) {
    int t = blockIdx.x * blockDim.x + threadIdx.x;
    int node = t >> 5, lane = t & 31;
    if (node >= NN) return;
    int start = ptr[node], n = cnt[node];
    float a0 = 0.0f, a1 = 0.0f;
    for (int j = lane; j < n; j += 32) {
        int2 e = csr[start + j];
        int r = e.x;
        float cf = __int_as_float(e.y) * dinv[r];
        float2 xv = *(const float2*)(x + 2 * r);
        a0 += cf * xv.x;
        a1 += cf * xv.y;
    }
    #pragma unroll
    for (int m = 16; m >= 1; m >>= 1) {
        a0 += __shfl_xor(a0, m, 32);
        a1 += __shfl_xor(a1, m, 32);
    }
    if (lane == 0) {
        float di = dinv[node];
        float2 xs = *(const float2*)(x + 2 * node);
        agg1[2 * node]     = di * a0 + di * di * xs.x;
        agg1[2 * node + 1] = di * a1 + di * di * xs.y;
    }
}

// ---------------- fused layer1 (LN+relu) + t2 = x1@W2 + agg2 init ----------------
__global__ void k_l1t2(const float* __restrict__ agg1, const float* __restrict__ x,
                       const float* __restrict__ dinv,
                       const float* __restrict__ W1, const float* __restrict__ b1,
                       const float* __restrict__ rW1, const float* __restrict__ rb1,
                       const float* __restrict__ g1, const float* __restrict__ be1,
                       const float* __restrict__ W2, const float* __restrict__ b2,
                       const float* __restrict__ rW2, const float* __restrict__ rb2,
                       float* __restrict__ t2, float* __restrict__ agg2) {
    __shared__ float sm[4][64];
    int wid = threadIdx.x >> 6, lane = threadIdx.x & 63;
    int node = blockIdx.x * 4 + wid;
    int nd = node < NN ? node : NN - 1;
    float a0 = agg1[2 * nd], a1 = agg1[2 * nd + 1];
    float xa = x[2 * nd], xb = x[2 * nd + 1];
    float v = a0 * W1[lane] + a1 * W1[64 + lane] + b1[lane]
            + xa * rW1[lane] + xb * rW1[64 + lane] + rb1[lane];
    float s = v;
    #pragma unroll
    for (int m = 32; m >= 1; m >>= 1) s += __shfl_xor(s, m, 64);
    float mean = s * (1.0f / 64.0f);
    float e = v - mean;
    float s2 = e * e;
    #pragma unroll
    for (int m = 32; m >= 1; m >>= 1) s2 += __shfl_xor(s2, m, 64);
    float var = s2 * (1.0f / 64.0f);
    float x1v = fmaxf(e * rsqrtf(var + LN_EPS) * g1[lane] + be1[lane], 0.0f);
    sm[wid][lane] = x1v;
    __syncthreads();
    int k = lane & 31;
    bool isres = lane >= 32;
    const float* Wm = isres ? rW2 : W2;
    float acc = 0.0f;
    #pragma unroll
    for (int j = 0; j < 64; ++j) acc += sm[wid][j] * Wm[j * 32 + k];
    float other = __shfl_xor(acc, 32, 64);
    if (node < NN && !isres) {
        t2[node * 32 + k] = acc;
        float di = dinv[node];
        agg2[node * 32 + k] = acc * di * di + b2[k] + other + rb2[k];
    }
}

// ---------------- layer 2 aggregation: gather (32 features, coalesced) ----------------
__global__ void k_agg2(const int* __restrict__ ptr, const int* __restrict__ cnt,
                       const int2* __restrict__ csr, const float* __restrict__ dinv,
                       const float* __restrict__ t2, float* __restrict__ agg2) {
    int t = blockIdx.x * blockDim.x + threadIdx.x;
    int node = t >> 5, k = t & 31;
    if (node >= NN) return;
    int start = ptr[node], n = cnt[node];
    float acc = 0.0f;
    #pragma unroll 4
    for (int j = 0; j < n; ++j) {
        int2 e = csr[start + j];             // lane-uniform broadcast
        int r = e.x;
        float cf = __int_as_float(e.y) * dinv[r];
        acc += cf * t2[r * 32 + k];          // 32-lane coalesced 128B
    }
    float di = dinv[node];
    agg2[node * 32 + k] += di * acc;
}

// ---------------- final: LN+relu, logits, proj, normalize ----------------
__global__ void k_final(const float* __restrict__ agg2,
                        const float* __restrict__ g2, const float* __restrict__ be2,
                        const float* __restrict__ fcW, const float* __restrict__ fcb,
                        const float* __restrict__ pW, const float* __restrict__ pb,
                        float* __restrict__ out) {
    int node = (blockIdx.x * blockDim.x + threadIdx.x) >> 5;
    int k = threadIdx.x & 31;
    if (node >= NN) return;
    float v = agg2[node * 32 + k];
    float s = v;
    #pragma unroll
    for (int m = 16; m >= 1; m >>= 1) s += __shfl_xor(s, m, 32);
    float mean = s * (1.0f / 32.0f);
    float e = v - mean;
    float s2 = e * e;
    #pragma unroll
    for (int m = 16; m >= 1; m >>= 1) s2 += __shfl_xor(s2, m, 32);
    float var = s2 * (1.0f / 32.0f);
    float x2 = fmaxf(e * rsqrtf(var + LN_EPS) * g2[k] + be2[k], 0.0f);
    float lg = x2 * fcW[k];
    #pragma unroll
    for (int m = 16; m >= 1; m >>= 1) lg += __shfl_xor(lg, m, 32);
    if (k == 0) out[node] = lg + fcb[0];
    float acc = pb[k];
    #pragma unroll
    for (int j = 0; j < 32; ++j) {
        float xj = __shfl(x2, j, 32);
        acc += xj * pW[j * 32 + k];
    }
    float n2 = acc * acc;
    #pragma unroll
    for (int m = 16; m >= 1; m >>= 1) n2 += __shfl_xor(n2, m, 32);
    float nrm = sqrtf(n2);
    out[NN + node * 32 + k] = acc / fmaxf(nrm, 1e-12f);
}

extern "C" void kernel_launch(void* const* d_in, const int* in_sizes, int n_in,
                              void* d_out, int out_size, void* d_ws, size_t ws_size,
                              hipStream_t stream) {
    const float* x   = (const float*)d_in[0];
    const float* ew  = (const float*)d_in[1];
    const float* W1  = (const float*)d_in[2];
    const float* b1  = (const float*)d_in[3];
    const float* rW1 = (const float*)d_in[4];
    const float* rb1 = (const float*)d_in[5];
    const float* g1  = (const float*)d_in[6];
    const float* be1 = (const float*)d_in[7];
    const float* W2  = (const float*)d_in[8];
    const float* b2  = (const float*)d_in[9];
    const float* rW2 = (const float*)d_in[10];
    const float* rb2 = (const float*)d_in[11];
    const float* g2  = (const float*)d_in[12];
    const float* be2 = (const float*)d_in[13];
    const float* fcW = (const float*)d_in[14];
    const float* fcb = (const float*)d_in[15];
    const float* pW  = (const float*)d_in[16];
    const float* pb  = (const float*)d_in[17];
    const int*   ei  = (const int*)d_in[18];
    const int* row = ei;
    const int* col = ei + NE;

    // workspace layout (csr first for 8B alignment; tmp aliases t2+agg2)
    char* p = (char*)d_ws;
    int2*  csr  = (int2*)p;            p += (size_t)NE * 8;
    float* dinv = (float*)p;           p += (size_t)NN * 4;
    float* agg1 = (float*)p;           p += (size_t)2 * NN * 4;
    float* t2   = (float*)p;           p += (size_t)32 * NN * 4;
    float* agg2 = (float*)p;           p += (size_t)32 * NN * 4;
    int*   cnt  = (int*)p;             p += (size_t)NN * 4;
    int*   ptr  = (int*)p;             p += (size_t)NN * 4;
    int*   gcur = (int*)p;             p += 256 * 4;
    int*   bsum = (int*)p;             p += 512 * 4;
    int2*  tmp  = (int2*)t2;           // 64*NN*4 = 25.6 MB, free until k_l1t2

    float* out = (float*)d_out;
    const int TB = 256;
    const int EB = (NE + TB - 1) / TB;
    const int NODE32 = (NN * 32 + TB - 1) / TB;

    hipMemsetAsync(cnt, 0, (size_t)NN * 4, stream);
    k_hist<<<EB, TB, 0, stream>>>(col, cnt);
    k_scan1<<<NBLK, 256, 0, stream>>>(cnt, bsum);
    k_scan2<<<1, 512, 0, stream>>>(bsum);
    k_scan3<<<NBLK, 256, 0, stream>>>(cnt, bsum, ptr);
    k_gcur<<<1, 256, 0, stream>>>(ptr, gcur);
    k_partA<<<NTILE, 256, 0, stream>>>(row, col, ew, gcur, tmp);
    k_partB<<<NBUCK, 512, 0, stream>>>(ptr, tmp, csr);
    k_deg<<<NODE32, TB, 0, stream>>>(ptr, cnt, csr, dinv);
    k_agg1<<<NODE32, TB, 0, stream>>>(ptr, cnt, csr, dinv, x, agg1);
    k_l1t2<<<(NN + 3) / 4, TB, 0, stream>>>(agg1, x, dinv, W1, b1, rW1, rb1, g1, be1,
                                            W2, b2, rW2, rb2, t2, agg2);
    k_agg2<<<NODE32, TB, 0, stream>>>(ptr, cnt, csr, dinv, t2, agg2);
    k_final<<<NODE32, TB, 0, stream>>>(agg2, g2, be2, fcW, fcb, pW, pb, out);
}

// Round 4
// 319.265 us; speedup vs baseline: 5.9174x; 1.3056x over previous
//
#include <hip/hip_runtime.h>

#define NN 100000
#define NE 3200000
#define LN_EPS 1e-5f
#define NBUCK 196       // ceil(NN/512), bucket = col >> 9
#define TILE 4096       // edges per partition block
#define NTILE 782       // ceil(NE/TILE)

// ---------------- bucket histogram (196 bins, LDS-privatized) ----------------
__global__ __launch_bounds__(256) void k_bhist(const int* __restrict__ col,
                                               int* __restrict__ bcnt) {
    __shared__ int lh[NBUCK];
    int t = threadIdx.x;
    for (int i = t; i < NBUCK; i += 256) lh[i] = 0;
    __syncthreads();
    long base = (long)blockIdx.x * TILE;
    int nt = (NE - base < TILE) ? (int)(NE - base) : TILE;   // always %4==0
    const int4* c4 = (const int4*)(col + base);
    int n4 = nt >> 2;
    for (int j = t; j < n4; j += 256) {
        int4 v = c4[j];
        atomicAdd(&lh[v.x >> 9], 1);
        atomicAdd(&lh[v.y >> 9], 1);
        atomicAdd(&lh[v.z >> 9], 1);
        atomicAdd(&lh[v.w >> 9], 1);
    }
    __syncthreads();
    for (int i = t; i < NBUCK; i += 256) {
        int v = lh[i];
        if (v) atomicAdd(&bcnt[i], v);
    }
}

// ---------------- bucket scan: bcnt -> bbase, init gcur, ptr[NN]=NE ----------------
__global__ void k_bscan(const int* __restrict__ bcnt, int* __restrict__ bbase,
                        int* __restrict__ gcur, int* __restrict__ ptr) {
    __shared__ int sm[256];
    int t = threadIdx.x;
    int v = (t < NBUCK) ? bcnt[t] : 0;
    sm[t] = v;
    __syncthreads();
    for (int off = 1; off < 256; off <<= 1) {
        int u = (t >= off) ? sm[t - off] : 0;
        __syncthreads();
        sm[t] += u;
        __syncthreads();
    }
    int ex = sm[t] - v;  // exclusive
    if (t < NBUCK) { bbase[t] = ex; gcur[t] = ex; }
    if (t == NBUCK - 1) bbase[NBUCK] = ex + v;   // = NE
    if (t == 0) ptr[NN] = NE;
}

// ---------------- partition pass A: bucket-sort tiles, near-coalesced flush ----------------
__global__ __launch_bounds__(256) void k_partA(
        const int* __restrict__ row, const int* __restrict__ col,
        const float* __restrict__ w, int* __restrict__ gcur,
        int2* __restrict__ tmp) {
    __shared__ int2 sbuf[TILE];     // 32 KB
    __shared__ int  gpos[TILE];     // 16 KB
    __shared__ int  lhist[NBUCK];
    __shared__ int  lofs[NBUCK];
    __shared__ int  lbase[NBUCK];
    __shared__ int  wsum[4];
    int t = threadIdx.x;
    long base_e = (long)blockIdx.x * TILE;
    int nt = NE - base_e < TILE ? (int)(NE - base_e) : TILE;

    for (int b = t; b < NBUCK; b += 256) lhist[b] = 0;
    __syncthreads();

    int er[16]; int ec[16]; float ewv[16];
    #pragma unroll
    for (int i = 0; i < 16; ++i) {
        int j = t + i * 256;
        if (j < nt) {
            int e = (int)base_e + j;
            er[i] = row[e]; ec[i] = col[e]; ewv[i] = w[e];
            atomicAdd(&lhist[ec[i] >> 9], 1);
        } else { er[i] = -1; ec[i] = 0; ewv[i] = 0.0f; }
    }
    __syncthreads();

    // block-exclusive-scan of lhist (padded to 256) + reserve global runs
    {
        int v = (t < NBUCK) ? lhist[t] : 0;
        int lane = t & 63;
        int inc = v;
        #pragma unroll
        for (int off = 1; off < 64; off <<= 1) {
            int u = __shfl_up(inc, off, 64);
            if (lane >= off) inc += u;
        }
        if (lane == 63) wsum[t >> 6] = inc;
        __syncthreads();
        int wv = t >> 6;
        int woff = 0;
        for (int j = 0; j < 4; ++j) if (j < wv) woff += wsum[j];
        if (t < NBUCK) {
            lofs[t] = woff + inc - v;
            lbase[t] = atomicAdd(&gcur[t], v);
        }
    }
    __syncthreads();
    for (int b = t; b < NBUCK; b += 256) lhist[b] = 0;   // reuse as rank counters
    __syncthreads();

    #pragma unroll
    for (int i = 0; i < 16; ++i) {
        if (er[i] >= 0) {
            int b = ec[i] >> 9;
            int r = atomicAdd(&lhist[b], 1);
            int slot = lofs[b] + r;
            sbuf[slot] = make_int2(er[i] | ((ec[i] & 511) << 17), __float_as_int(ewv[i]));
            gpos[slot] = lbase[b] + r;
        }
    }
    __syncthreads();

    #pragma unroll
    for (int i = 0; i < 16; ++i) {
        int j = t + i * 256;
        if (j < nt) tmp[gpos[j]] = sbuf[j];
    }
}

// ---------------- partition pass B: per-node count/scan -> ptr,dinv; scatter csr ----------------
__global__ __launch_bounds__(512) void k_partB(
        const int* __restrict__ bbase, const int2* __restrict__ tmp,
        int2* __restrict__ csr, int* __restrict__ ptr, float* __restrict__ dinv) {
    __shared__ int   nh[512];
    __shared__ float wsumf[512];
    __shared__ int   wscan[8];
    int b = blockIdx.x;
    int t = threadIdx.x;
    int start = bbase[b], end = bbase[b + 1];
    nh[t] = 0; wsumf[t] = 0.0f;
    __syncthreads();
    // pass 1: per-node count + weight sum (bucket region is L2-resident after this)
    for (int j = start + t; j < end; j += 512) {
        int2 rec = tmp[j];
        int cl = ((unsigned)rec.x) >> 17;
        atomicAdd(&nh[cl], 1);
        atomicAdd(&wsumf[cl], __int_as_float(rec.y));
    }
    __syncthreads();
    // block-exclusive scan of nh -> global per-node offsets
    int v = nh[t];
    int lane = t & 63;
    int inc = v;
    #pragma unroll
    for (int off = 1; off < 64; off <<= 1) {
        int u = __shfl_up(inc, off, 64);
        if (lane >= off) inc += u;
    }
    if (lane == 63) wscan[t >> 6] = inc;
    __syncthreads();
    int wv = t >> 6;
    int woff = 0;
    #pragma unroll
    for (int j = 0; j < 8; ++j) if (j < wv) woff += wscan[j];
    int ex = start + woff + inc - v;
    int gn = b * 512 + t;
    if (gn < NN) {
        ptr[gn] = ex;
        dinv[gn] = rsqrtf(wsumf[t] + 1.0f);   // +1 self-loop
    }
    __syncthreads();
    nh[t] = ex;   // cursors
    __syncthreads();
    // pass 2: scatter to exact per-node slots (reads hit L2)
    for (int j = start + t; j < end; j += 512) {
        int2 rec = tmp[j];
        int cl = ((unsigned)rec.x) >> 17;
        int r = rec.x & 0x1FFFF;
        int pos = atomicAdd(&nh[cl], 1);
        csr[pos] = make_int2(r, rec.y);
    }
}

// ---------------- layer 1 aggregation: gather (2 features) ----------------
__global__ void k_agg1(const int* __restrict__ ptr, const int2* __restrict__ csr,
                       const float* __restrict__ dinv, const float* __restrict__ x,
                       float* __restrict__ agg1) {
    int t = blockIdx.x * blockDim.x + threadIdx.x;
    int node = t >> 5, lane = t & 31;
    if (node >= NN) return;
    int start = ptr[node], n = ptr[node + 1] - start;
    float a0 = 0.0f, a1 = 0.0f;
    for (int j = lane; j < n; j += 32) {
        int2 e = csr[start + j];
        int r = e.x;
        float cf = __int_as_float(e.y) * dinv[r];
        float2 xv = *(const float2*)(x + 2 * r);
        a0 += cf * xv.x;
        a1 += cf * xv.y;
    }
    #pragma unroll
    for (int m = 16; m >= 1; m >>= 1) {
        a0 += __shfl_xor(a0, m, 32);
        a1 += __shfl_xor(a1, m, 32);
    }
    if (lane == 0) {
        float di = dinv[node];
        float2 xs = *(const float2*)(x + 2 * node);
        agg1[2 * node]     = di * a0 + di * di * xs.x;
        agg1[2 * node + 1] = di * a1 + di * di * xs.y;
    }
}

// ---------------- fused layer1 (LN+relu) + t2 = x1@W2 + agg2 init ----------------
__global__ void k_l1t2(const float* __restrict__ agg1, const float* __restrict__ x,
                       const float* __restrict__ dinv,
                       const float* __restrict__ W1, const float* __restrict__ b1,
                       const float* __restrict__ rW1, const float* __restrict__ rb1,
                       const float* __restrict__ g1, const float* __restrict__ be1,
                       const float* __restrict__ W2, const float* __restrict__ b2,
                       const float* __restrict__ rW2, const float* __restrict__ rb2,
                       float* __restrict__ t2, float* __restrict__ agg2) {
    __shared__ float sm[4][64];
    int wid = threadIdx.x >> 6, lane = threadIdx.x & 63;
    int node = blockIdx.x * 4 + wid;
    int nd = node < NN ? node : NN - 1;
    float a0 = agg1[2 * nd], a1 = agg1[2 * nd + 1];
    float xa = x[2 * nd], xb = x[2 * nd + 1];
    float v = a0 * W1[lane] + a1 * W1[64 + lane] + b1[lane]
            + xa * rW1[lane] + xb * rW1[64 + lane] + rb1[lane];
    float s = v;
    #pragma unroll
    for (int m = 32; m >= 1; m >>= 1) s += __shfl_xor(s, m, 64);
    float mean = s * (1.0f / 64.0f);
    float e = v - mean;
    float s2 = e * e;
    #pragma unroll
    for (int m = 32; m >= 1; m >>= 1) s2 += __shfl_xor(s2, m, 64);
    float var = s2 * (1.0f / 64.0f);
    float x1v = fmaxf(e * rsqrtf(var + LN_EPS) * g1[lane] + be1[lane], 0.0f);
    sm[wid][lane] = x1v;
    __syncthreads();
    int k = lane & 31;
    bool isres = lane >= 32;
    const float* Wm = isres ? rW2 : W2;
    float acc = 0.0f;
    #pragma unroll
    for (int j = 0; j < 64; ++j) acc += sm[wid][j] * Wm[j * 32 + k];
    float other = __shfl_xor(acc, 32, 64);
    if (node < NN && !isres) {
        t2[node * 32 + k] = acc;
        float di = dinv[node];
        agg2[node * 32 + k] = acc * di * di + b2[k] + other + rb2[k];
    }
}

// ---------------- layer 2 aggregation: gather (32 features, coalesced) ----------------
__global__ void k_agg2(const int* __restrict__ ptr, const int2* __restrict__ csr,
                       const float* __restrict__ dinv, const float* __restrict__ t2,
                       float* __restrict__ agg2) {
    int t = blockIdx.x * blockDim.x + threadIdx.x;
    int node = t >> 5, k = t & 31;
    if (node >= NN) return;
    int start = ptr[node], n = ptr[node + 1] - start;
    float acc = 0.0f;
    #pragma unroll 4
    for (int j = 0; j < n; ++j) {
        int2 e = csr[start + j];             // lane-uniform broadcast
        int r = e.x;
        float cf = __int_as_float(e.y) * dinv[r];
        acc += cf * t2[r * 32 + k];          // 32-lane coalesced 128B
    }
    float di = dinv[node];
    agg2[node * 32 + k] += di * acc;
}

// ---------------- final: LN+relu, logits, proj, normalize ----------------
__global__ void k_final(const float* __restrict__ agg2,
                        const float* __restrict__ g2, const float* __restrict__ be2,
                        const float* __restrict__ fcW, const float* __restrict__ fcb,
                        const float* __restrict__ pW, const float* __restrict__ pb,
                        float* __restrict__ out) {
    int node = (blockIdx.x * blockDim.x + threadIdx.x) >> 5;
    int k = threadIdx.x & 31;
    if (node >= NN) return;
    float v = agg2[node * 32 + k];
    float s = v;
    #pragma unroll
    for (int m = 16; m >= 1; m >>= 1) s += __shfl_xor(s, m, 32);
    float mean = s * (1.0f / 32.0f);
    float e = v - mean;
    float s2 = e * e;
    #pragma unroll
    for (int m = 16; m >= 1; m >>= 1) s2 += __shfl_xor(s2, m, 32);
    float var = s2 * (1.0f / 32.0f);
    float x2 = fmaxf(e * rsqrtf(var + LN_EPS) * g2[k] + be2[k], 0.0f);
    float lg = x2 * fcW[k];
    #pragma unroll
    for (int m = 16; m >= 1; m >>= 1) lg += __shfl_xor(lg, m, 32);
    if (k == 0) out[node] = lg + fcb[0];
    float acc = pb[k];
    #pragma unroll
    for (int j = 0; j < 32; ++j) {
        float xj = __shfl(x2, j, 32);
        acc += xj * pW[j * 32 + k];
    }
    float n2 = acc * acc;
    #pragma unroll
    for (int m = 16; m >= 1; m >>= 1) n2 += __shfl_xor(n2, m, 32);
    float nrm = sqrtf(n2);
    out[NN + node * 32 + k] = acc / fmaxf(nrm, 1e-12f);
}

extern "C" void kernel_launch(void* const* d_in, const int* in_sizes, int n_in,
                              void* d_out, int out_size, void* d_ws, size_t ws_size,
                              hipStream_t stream) {
    const float* x   = (const float*)d_in[0];
    const float* ew  = (const float*)d_in[1];
    const float* W1  = (const float*)d_in[2];
    const float* b1  = (const float*)d_in[3];
    const float* rW1 = (const float*)d_in[4];
    const float* rb1 = (const float*)d_in[5];
    const float* g1  = (const float*)d_in[6];
    const float* be1 = (const float*)d_in[7];
    const float* W2  = (const float*)d_in[8];
    const float* b2  = (const float*)d_in[9];
    const float* rW2 = (const float*)d_in[10];
    const float* rb2 = (const float*)d_in[11];
    const float* g2  = (const float*)d_in[12];
    const float* be2 = (const float*)d_in[13];
    const float* fcW = (const float*)d_in[14];
    const float* fcb = (const float*)d_in[15];
    const float* pW  = (const float*)d_in[16];
    const float* pb  = (const float*)d_in[17];
    const int*   ei  = (const int*)d_in[18];
    const int* row = ei;
    const int* col = ei + NE;

    // workspace layout (csr first for 8B alignment; tmp aliases t2+agg2)
    char* p = (char*)d_ws;
    int2*  csr   = (int2*)p;           p += (size_t)NE * 8;
    float* dinv  = (float*)p;          p += (size_t)NN * 4;
    float* agg1  = (float*)p;          p += (size_t)2 * NN * 4;
    float* t2    = (float*)p;          p += (size_t)32 * NN * 4;
    float* agg2  = (float*)p;          p += (size_t)32 * NN * 4;
    int*   ptr   = (int*)p;            p += (size_t)(NN + 1) * 4;
    int*   bcnt  = (int*)p;            p += 256 * 4;
    int*   bbase = (int*)p;            p += 256 * 4;
    int*   gcur  = (int*)p;            p += 256 * 4;
    int2*  tmp   = (int2*)t2;          // 25.6 MB, free until k_l1t2

    float* out = (float*)d_out;
    const int TB = 256;
    const int NODE32 = (NN * 32 + TB - 1) / TB;

    hipMemsetAsync(bcnt, 0, 256 * 4, stream);
    k_bhist<<<NTILE, 256, 0, stream>>>(col, bcnt);
    k_bscan<<<1, 256, 0, stream>>>(bcnt, bbase, gcur, ptr);
    k_partA<<<NTILE, 256, 0, stream>>>(row, col, ew, gcur, tmp);
    k_partB<<<NBUCK, 512, 0, stream>>>(bbase, tmp, csr, ptr, dinv);
    k_agg1<<<NODE32, TB, 0, stream>>>(ptr, csr, dinv, x, agg1);
    k_l1t2<<<(NN + 3) / 4, TB, 0, stream>>>(agg1, x, dinv, W1, b1, rW1, rb1, g1, be1,
                                            W2, b2, rW2, rb2, t2, agg2);
    k_agg2<<<NODE32, TB, 0, stream>>>(ptr, csr, dinv, t2, agg2);
    k_final<<<NODE32, TB, 0, stream>>>(agg2, g2, be2, fcW, fcb, pW, pb, out);
}

// Round 5
// 286.497 us; speedup vs baseline: 6.5942x; 1.1144x over previous
//
#include <hip/hip_runtime.h>
#include <hip/hip_bf16.h>

#define NN 100000
#define NE 3200000
#define LN_EPS 1e-5f
#define NBUCK 196       // ceil(NN/512), bucket = col >> 9
#define TILE 4096       // edges per partition block
#define NTILE 782       // ceil(NE/TILE)
#define L1NB 16         // nodes per k_l1t2 block (100000 = 6250 * 16 exactly)

// ---------------- bucket histogram (196 bins, LDS-privatized) ----------------
__global__ __launch_bounds__(256) void k_bhist(const int* __restrict__ col,
                                               int* __restrict__ bcnt) {
    __shared__ int lh[NBUCK];
    int t = threadIdx.x;
    for (int i = t; i < NBUCK; i += 256) lh[i] = 0;
    __syncthreads();
    long base = (long)blockIdx.x * TILE;
    int nt = (NE - base < TILE) ? (int)(NE - base) : TILE;   // always %4==0
    const int4* c4 = (const int4*)(col + base);
    int n4 = nt >> 2;
    for (int j = t; j < n4; j += 256) {
        int4 v = c4[j];
        atomicAdd(&lh[v.x >> 9], 1);
        atomicAdd(&lh[v.y >> 9], 1);
        atomicAdd(&lh[v.z >> 9], 1);
        atomicAdd(&lh[v.w >> 9], 1);
    }
    __syncthreads();
    for (int i = t; i < NBUCK; i += 256) {
        int v = lh[i];
        if (v) atomicAdd(&bcnt[i], v);
    }
}

// ---------------- bucket scan: bcnt -> bbase, init gcur, ptr[NN]=NE ----------------
__global__ void k_bscan(const int* __restrict__ bcnt, int* __restrict__ bbase,
                        int* __restrict__ gcur, int* __restrict__ ptr) {
    __shared__ int sm[256];
    int t = threadIdx.x;
    int v = (t < NBUCK) ? bcnt[t] : 0;
    sm[t] = v;
    __syncthreads();
    for (int off = 1; off < 256; off <<= 1) {
        int u = (t >= off) ? sm[t - off] : 0;
        __syncthreads();
        sm[t] += u;
        __syncthreads();
    }
    int ex = sm[t] - v;  // exclusive
    if (t < NBUCK) { bbase[t] = ex; gcur[t] = ex; }
    if (t == NBUCK - 1) bbase[NBUCK] = ex + v;   // = NE
    if (t == 0) ptr[NN] = NE;
}

// ---------------- partition pass A: bucket-sort tiles, near-coalesced flush ----------------
__global__ __launch_bounds__(256) void k_partA(
        const int* __restrict__ row, const int* __restrict__ col,
        const float* __restrict__ w, int* __restrict__ gcur,
        int2* __restrict__ tmp) {
    __shared__ int2 sbuf[TILE];     // 32 KB
    __shared__ int  gpos[TILE];     // 16 KB
    __shared__ int  lhist[NBUCK];
    __shared__ int  lofs[NBUCK];
    __shared__ int  lbase[NBUCK];
    __shared__ int  wsum[4];
    int t = threadIdx.x;
    long base_e = (long)blockIdx.x * TILE;
    int nt = NE - base_e < TILE ? (int)(NE - base_e) : TILE;

    for (int b = t; b < NBUCK; b += 256) lhist[b] = 0;
    __syncthreads();

    int er[16]; int ec[16]; float ewv[16];
    #pragma unroll
    for (int i = 0; i < 16; ++i) {
        int j = t + i * 256;
        if (j < nt) {
            int e = (int)base_e + j;
            er[i] = row[e]; ec[i] = col[e]; ewv[i] = w[e];
            atomicAdd(&lhist[ec[i] >> 9], 1);
        } else { er[i] = -1; ec[i] = 0; ewv[i] = 0.0f; }
    }
    __syncthreads();

    // block-exclusive-scan of lhist (padded to 256) + reserve global runs
    {
        int v = (t < NBUCK) ? lhist[t] : 0;
        int lane = t & 63;
        int inc = v;
        #pragma unroll
        for (int off = 1; off < 64; off <<= 1) {
            int u = __shfl_up(inc, off, 64);
            if (lane >= off) inc += u;
        }
        if (lane == 63) wsum[t >> 6] = inc;
        __syncthreads();
        int wv = t >> 6;
        int woff = 0;
        for (int j = 0; j < 4; ++j) if (j < wv) woff += wsum[j];
        if (t < NBUCK) {
            lofs[t] = woff + inc - v;
            lbase[t] = atomicAdd(&gcur[t], v);
        }
    }
    __syncthreads();
    for (int b = t; b < NBUCK; b += 256) lhist[b] = 0;   // reuse as rank counters
    __syncthreads();

    #pragma unroll
    for (int i = 0; i < 16; ++i) {
        if (er[i] >= 0) {
            int b = ec[i] >> 9;
            int r = atomicAdd(&lhist[b], 1);
            int slot = lofs[b] + r;
            sbuf[slot] = make_int2(er[i] | ((ec[i] & 511) << 17), __float_as_int(ewv[i]));
            gpos[slot] = lbase[b] + r;
        }
    }
    __syncthreads();

    #pragma unroll
    for (int i = 0; i < 16; ++i) {
        int j = t + i * 256;
        if (j < nt) tmp[gpos[j]] = sbuf[j];
    }
}

// ---------------- partition pass B: per-node count/scan -> ptr,dinv; scatter csr ----------------
__global__ __launch_bounds__(512) void k_partB(
        const int* __restrict__ bbase, const int2* __restrict__ tmp,
        int2* __restrict__ csr, int* __restrict__ ptr, float* __restrict__ dinv) {
    __shared__ int   nh[512];
    __shared__ float wsumf[512];
    __shared__ int   wscan[8];
    int b = blockIdx.x;
    int t = threadIdx.x;
    int start = bbase[b], end = bbase[b + 1];
    nh[t] = 0; wsumf[t] = 0.0f;
    __syncthreads();
    // pass 1: per-node count + weight sum (bucket region is L2-resident after this)
    for (int j = start + t; j < end; j += 512) {
        int2 rec = tmp[j];
        int cl = ((unsigned)rec.x) >> 17;
        atomicAdd(&nh[cl], 1);
        atomicAdd(&wsumf[cl], __int_as_float(rec.y));
    }
    __syncthreads();
    // block-exclusive scan of nh -> global per-node offsets
    int v = nh[t];
    int lane = t & 63;
    int inc = v;
    #pragma unroll
    for (int off = 1; off < 64; off <<= 1) {
        int u = __shfl_up(inc, off, 64);
        if (lane >= off) inc += u;
    }
    if (lane == 63) wscan[t >> 6] = inc;
    __syncthreads();
    int wv = t >> 6;
    int woff = 0;
    #pragma unroll
    for (int j = 0; j < 8; ++j) if (j < wv) woff += wscan[j];
    int ex = start + woff + inc - v;
    int gn = b * 512 + t;
    if (gn < NN) {
        ptr[gn] = ex;
        dinv[gn] = rsqrtf(wsumf[t] + 1.0f);   // +1 self-loop
    }
    __syncthreads();
    nh[t] = ex;   // cursors
    __syncthreads();
    // pass 2: scatter to exact per-node slots (reads hit L2)
    for (int j = start + t; j < end; j += 512) {
        int2 rec = tmp[j];
        int cl = ((unsigned)rec.x) >> 17;
        int r = rec.x & 0x1FFFF;
        int pos = atomicAdd(&nh[cl], 1);
        csr[pos] = make_int2(r, rec.y);
    }
}

// ---------------- layer 1 aggregation: gather (2 features) ----------------
__global__ void k_agg1(const int* __restrict__ ptr, const int2* __restrict__ csr,
                       const float* __restrict__ dinv, const float* __restrict__ x,
                       float* __restrict__ agg1) {
    int t = blockIdx.x * blockDim.x + threadIdx.x;
    int node = t >> 5, lane = t & 31;
    if (node >= NN) return;
    int start = ptr[node], n = ptr[node + 1] - start;
    float a0 = 0.0f, a1 = 0.0f;
    for (int j = lane; j < n; j += 32) {
        int2 e = csr[start + j];
        int r = e.x;
        float cf = __int_as_float(e.y) * dinv[r];
        float2 xv = *(const float2*)(x + 2 * r);
        a0 += cf * xv.x;
        a1 += cf * xv.y;
    }
    #pragma unroll
    for (int m = 16; m >= 1; m >>= 1) {
        a0 += __shfl_xor(a0, m, 32);
        a1 += __shfl_xor(a1, m, 32);
    }
    if (lane == 0) {
        float di = dinv[node];
        float2 xs = *(const float2*)(x + 2 * node);
        agg1[2 * node]     = di * a0 + di * di * xs.x;
        agg1[2 * node + 1] = di * a1 + di * di * xs.y;
    }
}

// ---------------- fused layer1 (LN+relu) + t2s = dinv*(x1@W2) [bf16] + agg2 init ----------------
// 16 nodes/block; weights [W2|rW2] transposed in LDS (pad 68 -> conflict-free b128)
__global__ __launch_bounds__(256) void k_l1t2(
        const float* __restrict__ agg1, const float* __restrict__ x,
        const float* __restrict__ dinv,
        const float* __restrict__ W1, const float* __restrict__ b1,
        const float* __restrict__ rW1, const float* __restrict__ rb1,
        const float* __restrict__ g1, const float* __restrict__ be1,
        const float* __restrict__ W2, const float* __restrict__ b2,
        const float* __restrict__ rW2, const float* __restrict__ rb2,
        __hip_bfloat16* __restrict__ t2, float* __restrict__ agg2) {
    __shared__ float wT[64][68];   // wT[o][j]: o<32 -> W2[j][o], o>=32 -> rW2[j][o-32]
    __shared__ float xs[L1NB][68]; // x1 rows, 272B stride (16B aligned)
    int tid = threadIdx.x;
    // stage weights (once per block)
    for (int i = tid; i < 4096; i += 256) {
        int j = i >> 6, o = i & 63;
        wT[o][j] = (o < 32) ? W2[j * 32 + o] : rW2[j * 32 + (o - 32)];
    }
    int wid = tid >> 6, lane = tid & 63;
    int base = blockIdx.x * L1NB;
    // hoist lane-invariant params
    float w10 = W1[lane], w11 = W1[64 + lane];
    float r10 = rW1[lane], r11 = rW1[64 + lane];
    float bb = b1[lane] + rb1[lane];
    float gg = g1[lane], be = be1[lane];
    // LN phase: wave wid handles nodes base+wid*4 .. +3
    #pragma unroll
    for (int sub = 0; sub < 4; ++sub) {
        int n = base + wid * 4 + sub;
        float a0 = agg1[2 * n], a1 = agg1[2 * n + 1];
        float xa = x[2 * n], xb = x[2 * n + 1];
        float v = a0 * w10 + a1 * w11 + xa * r10 + xb * r11 + bb;
        float s = v;
        #pragma unroll
        for (int m = 32; m >= 1; m >>= 1) s += __shfl_xor(s, m, 64);
        float mean = s * (1.0f / 64.0f);
        float e = v - mean;
        float s2 = e * e;
        #pragma unroll
        for (int m = 32; m >= 1; m >>= 1) s2 += __shfl_xor(s2, m, 64);
        float var = s2 * (1.0f / 64.0f);
        xs[wid * 4 + sub][lane] = fmaxf(e * rsqrtf(var + LN_EPS) * gg + be, 0.0f);
    }
    __syncthreads();
    // GEMV phase: lane o computes output o for nodes g, g+4, g+8, g+12
    int o = lane, g = wid;
    const float4* wrow = (const float4*)&wT[o][0];
    const float4* x0 = (const float4*)&xs[g][0];
    const float4* x1r = (const float4*)&xs[g + 4][0];
    const float4* x2r = (const float4*)&xs[g + 8][0];
    const float4* x3r = (const float4*)&xs[g + 12][0];
    float acc0 = 0.0f, acc1 = 0.0f, acc2 = 0.0f, acc3 = 0.0f;
    #pragma unroll
    for (int jq = 0; jq < 16; ++jq) {
        float4 wv = wrow[jq];
        float4 a = x0[jq], b = x1r[jq], c = x2r[jq], d = x3r[jq];
        acc0 += wv.x * a.x + wv.y * a.y + wv.z * a.z + wv.w * a.w;
        acc1 += wv.x * b.x + wv.y * b.y + wv.z * b.z + wv.w * b.w;
        acc2 += wv.x * c.x + wv.y * c.y + wv.z * c.z + wv.w * c.w;
        acc3 += wv.x * d.x + wv.y * d.y + wv.z * d.z + wv.w * d.w;
    }
    // exchange: lane o (<32) holds W2-dot, lane o+32 holds rW2-dot of same node
    float res0 = __shfl_xor(acc0, 32, 64);
    float res1 = __shfl_xor(acc1, 32, 64);
    float res2 = __shfl_xor(acc2, 32, 64);
    float res3 = __shfl_xor(acc3, 32, 64);
    if (o < 32) {
        float accs[4] = {acc0, acc1, acc2, acc3};
        float ress[4] = {res0, res1, res2, res3};
        #pragma unroll
        for (int i = 0; i < 4; ++i) {
            int n = base + g + 4 * i;
            float di = dinv[n];
            t2[n * 32 + o] = __float2bfloat16(accs[i] * di);   // pre-scaled by dinv[src]
            agg2[n * 32 + o] = accs[i] * di * di + b2[o] + ress[i] + rb2[o];
        }
    }
}

// ---------------- layer 2 aggregation: gather (32 features, bf16 t2s) ----------------
__global__ void k_agg2(const int* __restrict__ ptr, const int2* __restrict__ csr,
                       const float* __restrict__ dinv,
                       const __hip_bfloat16* __restrict__ t2,
                       float* __restrict__ agg2) {
    int t = blockIdx.x * blockDim.x + threadIdx.x;
    int node = t >> 5, k = t & 31;
    if (node >= NN) return;
    int start = ptr[node], n = ptr[node + 1] - start;
    float acc = 0.0f;
    #pragma unroll 4
    for (int j = 0; j < n; ++j) {
        int2 e = csr[start + j];             // lane-uniform broadcast
        int r = e.x;
        float cf = __int_as_float(e.y);      // t2 already carries dinv[r]
        acc += cf * __bfloat162float(t2[r * 32 + k]);   // 64B coalesced gather
    }
    float di = dinv[node];
    agg2[node * 32 + k] += di * acc;
}

// ---------------- final: LN+relu, logits, proj, normalize ----------------
__global__ void k_final(const float* __restrict__ agg2,
                        const float* __restrict__ g2, const float* __restrict__ be2,
                        const float* __restrict__ fcW, const float* __restrict__ fcb,
                        const float* __restrict__ pW, const float* __restrict__ pb,
                        float* __restrict__ out) {
    int node = (blockIdx.x * blockDim.x + threadIdx.x) >> 5;
    int k = threadIdx.x & 31;
    if (node >= NN) return;
    float v = agg2[node * 32 + k];
    float s = v;
    #pragma unroll
    for (int m = 16; m >= 1; m >>= 1) s += __shfl_xor(s, m, 32);
    float mean = s * (1.0f / 32.0f);
    float e = v - mean;
    float s2 = e * e;
    #pragma unroll
    for (int m = 16; m >= 1; m >>= 1) s2 += __shfl_xor(s2, m, 32);
    float var = s2 * (1.0f / 32.0f);
    float x2 = fmaxf(e * rsqrtf(var + LN_EPS) * g2[k] + be2[k], 0.0f);
    float lg = x2 * fcW[k];
    #pragma unroll
    for (int m = 16; m >= 1; m >>= 1) lg += __shfl_xor(lg, m, 32);
    if (k == 0) out[node] = lg + fcb[0];
    float acc = pb[k];
    #pragma unroll
    for (int j = 0; j < 32; ++j) {
        float xj = __shfl(x2, j, 32);
        acc += xj * pW[j * 32 + k];
    }
    float n2 = acc * acc;
    #pragma unroll
    for (int m = 16; m >= 1; m >>= 1) n2 += __shfl_xor(n2, m, 32);
    float nrm = sqrtf(n2);
    out[NN + node * 32 + k] = acc / fmaxf(nrm, 1e-12f);
}

extern "C" void kernel_launch(void* const* d_in, const int* in_sizes, int n_in,
                              void* d_out, int out_size, void* d_ws, size_t ws_size,
                              hipStream_t stream) {
    const float* x   = (const float*)d_in[0];
    const float* ew  = (const float*)d_in[1];
    const float* W1  = (const float*)d_in[2];
    const float* b1  = (const float*)d_in[3];
    const float* rW1 = (const float*)d_in[4];
    const float* rb1 = (const float*)d_in[5];
    const float* g1  = (const float*)d_in[6];
    const float* be1 = (const float*)d_in[7];
    const float* W2  = (const float*)d_in[8];
    const float* b2  = (const float*)d_in[9];
    const float* rW2 = (const float*)d_in[10];
    const float* rb2 = (const float*)d_in[11];
    const float* g2  = (const float*)d_in[12];
    const float* be2 = (const float*)d_in[13];
    const float* fcW = (const float*)d_in[14];
    const float* fcb = (const float*)d_in[15];
    const float* pW  = (const float*)d_in[16];
    const float* pb  = (const float*)d_in[17];
    const int*   ei  = (const int*)d_in[18];
    const int* row = ei;
    const int* col = ei + NE;

    // workspace layout (csr first for 8B alignment; tmp aliases t2+agg2)
    char* p = (char*)d_ws;
    int2*  csr   = (int2*)p;           p += (size_t)NE * 8;
    float* dinv  = (float*)p;          p += (size_t)NN * 4;
    float* agg1  = (float*)p;          p += (size_t)2 * NN * 4;
    __hip_bfloat16* t2 = (__hip_bfloat16*)p;  p += (size_t)32 * NN * 4;  // region kept fp32-sized
    float* agg2  = (float*)p;          p += (size_t)32 * NN * 4;
    int*   ptr   = (int*)p;            p += (size_t)(NN + 1) * 4;
    int*   bcnt  = (int*)p;            p += 256 * 4;
    int*   bbase = (int*)p;            p += 256 * 4;
    int*   gcur  = (int*)p;            p += 256 * 4;
    int2*  tmp   = (int2*)t2;          // 25.6 MB (t2+agg2 regions), free until k_l1t2

    float* out = (float*)d_out;
    const int TB = 256;
    const int NODE32 = (NN * 32 + TB - 1) / TB;

    hipMemsetAsync(bcnt, 0, 256 * 4, stream);
    k_bhist<<<NTILE, 256, 0, stream>>>(col, bcnt);
    k_bscan<<<1, 256, 0, stream>>>(bcnt, bbase, gcur, ptr);
    k_partA<<<NTILE, 256, 0, stream>>>(row, col, ew, gcur, tmp);
    k_partB<<<NBUCK, 512, 0, stream>>>(bbase, tmp, csr, ptr, dinv);
    k_agg1<<<NODE32, TB, 0, stream>>>(ptr, csr, dinv, x, agg1);
    k_l1t2<<<NN / L1NB, 256, 0, stream>>>(agg1, x, dinv, W1, b1, rW1, rb1, g1, be1,
                                          W2, b2, rW2, rb2, t2, agg2);
    k_agg2<<<NODE32, TB, 0, stream>>>(ptr, csr, dinv, t2, agg2);
    k_final<<<NODE32, TB, 0, stream>>>(agg2, g2, be2, fcW, fcb, pW, pb, out);
}